// Round 6
// baseline (704.716 us; speedup 1.0000x reference)
//
#include <hip/hip_runtime.h>
#include <cstddef>

#define NB 2
#define NH 16
#define SQ 2048
#define DM 1024
#define DH 64
#define WN 128

using half8  = __attribute__((ext_vector_type(8))) _Float16;
using half4  = __attribute__((ext_vector_type(4))) _Float16;
using floatx4 = __attribute__((ext_vector_type(4))) float;

__device__ __forceinline__ void gl_lds16(const _Float16* g, _Float16* l) {
    __builtin_amdgcn_global_load_lds(
        (const __attribute__((address_space(1))) void*)g,
        (__attribute__((address_space(3))) void*)l, 16, 0, 0);
}

// ---------------------------------------------------------------------------
// Zero-fill of the out-of-band attn region: a fill-clone (no barriers, no
// compute, pure grid-stride streaming stores) — the configuration measured
// at 6.3 TB/s by the harness's own fillBuffer. Launched FIRST (zeros depend
// on nothing); band float4 tiles are disjoint (wo 16-aligned, window 272).
// ---------------------------------------------------------------------------
__global__ __launch_bounds__(256) void zfill_attn(float4* __restrict__ attn4)
{
    const size_t stride = (size_t)gridDim.x * 256;
    constexpr size_t TOT = (size_t)NB * NH * SQ * (SQ / 4);  // 33,554,432
    const float4 z4 = make_float4(0.f, 0.f, 0.f, 0.f);
    for (size_t idx = (size_t)blockIdx.x * 256 + threadIdx.x; idx < TOT;
         idx += stride) {
        const int i  = (int)((idx >> 9) & (SQ - 1));   // query row
        const int c4 = ((int)idx & 511) << 2;          // col of this float4
        const int wo = ((i >> 4) << 4) - WN;           // tile window origin
        if ((unsigned)(c4 - wo) >= 272u) attn4[idx] = z4;
    }
}

// ---------------------------------------------------------------------------
// fp32 -> fp16 converter, fused: y=0 -> x tensor, y=1..4 -> the 4 weights.
// ---------------------------------------------------------------------------
__global__ __launch_bounds__(256) void cvt5(
    const float* __restrict__ sx,
    const float* __restrict__ s1, const float* __restrict__ s2,
    const float* __restrict__ s3, const float* __restrict__ s4,
    _Float16* __restrict__ dx,
    _Float16* __restrict__ d1, _Float16* __restrict__ d2,
    _Float16* __restrict__ d3, _Float16* __restrict__ d4,
    int n8x, int n8w)
{
    const int y = blockIdx.y;
    const float* s = (y == 0) ? sx : (y == 1) ? s1 : (y == 2) ? s2
                   : (y == 3) ? s3 : s4;
    _Float16*   d = (y == 0) ? dx : (y == 1) ? d1 : (y == 2) ? d2
                   : (y == 3) ? d3 : d4;
    const int n8 = (y == 0) ? n8x : n8w;
    int idx = blockIdx.x * 256 + threadIdx.x;
    if (idx < n8) {
        const float4 a = ((const float4*)s)[idx * 2];
        const float4 b = ((const float4*)s)[idx * 2 + 1];
        half8 h;
        h[0] = (_Float16)a.x; h[1] = (_Float16)a.y;
        h[2] = (_Float16)a.z; h[3] = (_Float16)a.w;
        h[4] = (_Float16)b.x; h[5] = (_Float16)b.y;
        h[6] = (_Float16)b.z; h[7] = (_Float16)b.w;
        ((half8*)d)[idx] = h;
    }
}

// ---------------------------------------------------------------------------
// fp16 MFMA GEMM (m97 structure): C = A @ W^T + bias.
// BN = output-tile width (128 for QKV; 64 for out-proj -> 512 blocks, 2+/CU).
// ---------------------------------------------------------------------------
template <int OUT_HALF, int BN>
__global__ __launch_bounds__(256) void gemm_h(
    const _Float16* __restrict__ A,
    const _Float16* __restrict__ W0, const _Float16* __restrict__ W1,
    const _Float16* __restrict__ W2,
    const float* __restrict__ b0, const float* __restrict__ b1,
    const float* __restrict__ b2,
    void* __restrict__ O0, void* __restrict__ O1, void* __restrict__ O2)
{
    constexpr int K = DM, N = DM, BK = 64;
    constexpr int NF = BN / 32;          // n-frags per wave (4 or 2)

    const _Float16* Wp = (blockIdx.z == 0) ? W0 : (blockIdx.z == 1) ? W1 : W2;
    const float*    bb = (blockIdx.z == 0) ? b0 : (blockIdx.z == 1) ? b1 : b2;
    void*           Op = (blockIdx.z == 0) ? O0 : (blockIdx.z == 1) ? O1 : O2;

    __shared__ _Float16 Asl[128 * BK];   // 16 KB
    __shared__ _Float16 Bsl[BN * BK];    // 16 or 8 KB

    const int tid  = threadIdx.x;
    const int lane = tid & 63;
    const int w    = tid >> 6;          // wave 0..3
    const int wm   = w & 1, wn = w >> 1;
    const int m0   = blockIdx.y * 128;
    const int n0   = blockIdx.x * BN;

    const int l8 = lane >> 3;           // row within 8-row group
    const int lc = lane & 7;            // 16B chunk within row

    floatx4 acc[4][NF];
#pragma unroll
    for (int t = 0; t < 4; ++t)
#pragma unroll
        for (int u = 0; u < NF; ++u) acc[t][u] = (floatx4){0.f, 0.f, 0.f, 0.f};

    for (int k0 = 0; k0 < K; k0 += BK) {
        __syncthreads();                 // prior iter's LDS reads done
#pragma unroll
        for (int i = 0; i < 4; ++i) {    // A rows 0..127
            const int r  = w * 8 + l8 + i * 32;
            const int ca = lc ^ (r & 7);             // swizzled chunk
            gl_lds16(A + (size_t)(m0 + r) * K + k0 + ca * 8,
                     Asl + r * BK + lc * 8);
        }
#pragma unroll
        for (int i = 0; i < BN / 32; ++i) {          // B rows 0..BN-1
            const int r  = w * 8 + l8 + i * 32;
            const int ca = lc ^ (r & 7);
            gl_lds16(Wp + (size_t)(n0 + r) * K + k0 + ca * 8,
                     Bsl + r * BK + lc * 8);
        }
        __syncthreads();                 // drain global_load_lds
#pragma unroll
        for (int kk = 0; kk < BK; kk += 32) {
            half8 af[4], bf[NF];
            const int q = (kk >> 3) + (lane >> 4);   // chunk idx 0..7
#pragma unroll
            for (int t = 0; t < 4; ++t) {
                const int ra = wm * 64 + t * 16 + (lane & 15);
                af[t] = *(const half8*)(Asl + ra * BK + ((q ^ (ra & 7)) << 3));
            }
#pragma unroll
            for (int u = 0; u < NF; ++u) {
                const int rb = wn * (BN / 2) + u * 16 + (lane & 15);
                bf[u] = *(const half8*)(Bsl + rb * BK + ((q ^ (rb & 7)) << 3));
            }
#pragma unroll
            for (int t = 0; t < 4; ++t)
#pragma unroll
                for (int u = 0; u < NF; ++u)
                    acc[t][u] = __builtin_amdgcn_mfma_f32_16x16x32_f16(
                        af[t], bf[u], acc[t][u], 0, 0, 0);
        }
    }

    // epilogue: C/D layout col=lane&15, row=(lane>>4)*4+reg
    const int col0 = n0 + wn * (BN / 2) + (lane & 15);
    const int row0 = m0 + wm * 64 + ((lane >> 4) << 2);
#pragma unroll
    for (int u = 0; u < NF; ++u) {
        const int n = col0 + u * 16;
        const float bias = bb[n];
#pragma unroll
        for (int t = 0; t < 4; ++t) {
            const int m = row0 + t * 16;
#pragma unroll
            for (int r = 0; r < 4; ++r) {
                const float v = acc[t][u][r] + bias;
                if (OUT_HALF)
                    ((_Float16*)Op)[(size_t)(m + r) * N + n] = (_Float16)v;
                else
                    ((float*)Op)[(size_t)(m + r) * N + n] = v;
            }
        }
    }
}

// ---------------------------------------------------------------------------
// Sliding-window attention v8: v5 core (MFMA QK^T + MFMA PV) with
//  - band-only attn writes (zeros handled by zfill_attn)
//  - bijective XCD-chunk swizzle: 4096 blocks -> each XCD owns 4 whole
//    (b,h) heads; K+V working set 2 MB < 4 MB L2 -> staging L2-resident.
// ---------------------------------------------------------------------------
__global__ __launch_bounds__(256) void attn_mfma(
    const _Float16* __restrict__ Q, const _Float16* __restrict__ K,
    const _Float16* __restrict__ V, float* __restrict__ attn,
    _Float16* __restrict__ ctx)
{
    const int tid  = threadIdx.x;
    const int lane = tid & 63;
    const int w    = tid >> 6;            // wave 0..3

    // XCD-chunk swizzle (4096 % 8 == 0 -> bijective)
    const int f    = blockIdx.x + 128 * (blockIdx.y + 16 * blockIdx.z);
    const int newf = (f & 7) * 512 + (f >> 3);
    const int qt   = newf & 127;
    const int h    = (newf >> 7) & 15;
    const int b    = newf >> 11;

    const int i0 = qt * 16;
    const int wo = i0 - WN;               // window origin (multiple of 16)

    __shared__ _Float16 KV[64 * 320];     // 40 KB: K[272][64] then Vt[64][320]
    __shared__ _Float16 Qs[16 * 64];      // 2 KB
    __shared__ float    Sl[16 * 276];     // 17.25 KB (276: 2-way-free stride)
    __shared__ _Float16 Pl[16 * 320];     // 10 KB

    const int l8 = lane >> 3;             // row in 8-row stage group
    const int lc = lane & 7;              // 16B chunk in row

    // ---- phase 1: stage K rows 0..255 (all waves) ----
#pragma unroll
    for (int i = 0; i < 8; ++i) {
        const int r  = w * 8 + l8 + i * 32;
        const int jg = wo + r;
        const int jc = jg < 0 ? 0 : (jg >= SQ ? SQ - 1 : jg);
        const int ca = lc ^ (r & 7);
        gl_lds16(K + ((size_t)(b * SQ + jc)) * DM + h * DH + ca * 8,
                 KV + r * 64 + lc * 8);
    }
    if (w < 2) {                          // K rows 256..271
        const int r  = 256 + w * 8 + l8;
        const int jg = wo + r;
        const int jc = jg >= SQ ? SQ - 1 : jg;
        const int ca = lc ^ (r & 7);
        gl_lds16(K + ((size_t)(b * SQ + jc)) * DM + h * DH + ca * 8,
                 KV + r * 64 + lc * 8);
    } else {                              // Q rows 0..15 (waves 2,3)
        const int r  = (w - 2) * 8 + l8;
        const int ca = lc ^ (r & 7);
        gl_lds16(Q + ((size_t)(b * SQ + i0 + r)) * DM + h * DH + ca * 8,
                 Qs + r * 64 + lc * 8);
    }

    // V window -> registers (288 rows x 8 chunks = 9 tasks/thread exactly)
    half8 vr[9];
#pragma unroll
    for (int it = 0; it < 9; ++it) {
        const int idx = tid + 256 * it;
        const int j = idx >> 3, c8 = idx & 7;
        const int jg = wo + j;
        const int jc = jg < 0 ? 0 : (jg >= SQ ? SQ - 1 : jg);
        vr[it] = *(const half8*)(V + ((size_t)(b * SQ + jc)) * DM + h * DH + c8 * 8);
    }

    __syncthreads();                      // K/Q staged (drains vmcnt)

    // ---- phase 3: QK^T ----
    half8 af0, af1;
    {
        const int row = lane & 15;
        af0 = *(const half8*)(Qs + row * 64 + ((((lane >> 4))     ^ (row & 7)) << 3));
        af1 = *(const half8*)(Qs + row * 64 + (((4 + (lane >> 4)) ^ (row & 7)) << 3));
    }
    for (int t = w; t < 17; t += 4) {
        const int rb = t * 16 + (lane & 15);
        half8 bf0 = *(const half8*)(KV + rb * 64 + ((((lane >> 4))     ^ (rb & 7)) << 3));
        half8 bf1 = *(const half8*)(KV + rb * 64 + (((4 + (lane >> 4)) ^ (rb & 7)) << 3));
        floatx4 acc = (floatx4){0.f, 0.f, 0.f, 0.f};
        acc = __builtin_amdgcn_mfma_f32_16x16x32_f16(af0, bf0, acc, 0, 0, 0);
        acc = __builtin_amdgcn_mfma_f32_16x16x32_f16(af1, bf1, acc, 0, 0, 0);
        const int jloc = t * 16 + (lane & 15);
        const int jg   = wo + jloc;
        const bool inr = (jg >= 0) && (jg < SQ);
#pragma unroll
        for (int r = 0; r < 4; ++r) {
            const int q = ((lane >> 4) << 2) + r;
            const bool valid = ((unsigned)(jloc - q) <= 256u) && inr;
            Sl[q * 276 + jloc] = valid ? acc[r] * 0.125f : -1e30f;
        }
    }
    __syncthreads();                      // S complete, K reads done

    // ---- phase 5a: scatter V^T into KV (K buffer dead) ----
#pragma unroll
    for (int it = 0; it < 9; ++it) {
        const int idx = tid + 256 * it;
        const int j = idx >> 3, c8 = idx & 7;
        const int jc3 = j >> 3, jl = j & 7;
#pragma unroll
        for (int e = 0; e < 8; ++e) {
            const int d = c8 * 8 + e;     // d>>3 == c8, f(d) = (c8+e)&7
            KV[d * 320 + ((jc3 ^ ((c8 + e) & 7)) << 3) + jl] = vr[it][e];
        }
    }

    // ---- phase 5b: softmax + P fp16 + band attn writes ----
    for (int q = w; q < 16; q += 4) {
        const float* Srow = Sl + q * 276;
        const float v0 = Srow[lane];
        const float v1 = Srow[lane + 64];
        const float v2 = Srow[lane + 128];
        const float v3 = Srow[lane + 192];
        const float v4 = (lane < 16) ? Srow[lane + 256] : -1e30f;
        float m = fmaxf(fmaxf(fmaxf(v0, v1), fmaxf(v2, v3)), v4);
        m = fmaxf(m, __shfl_xor(m, 32));
        m = fmaxf(m, __shfl_xor(m, 16));
        m = fmaxf(m, __shfl_xor(m, 8));
        m = fmaxf(m, __shfl_xor(m, 4));
        m = fmaxf(m, __shfl_xor(m, 2));
        m = fmaxf(m, __shfl_xor(m, 1));
        float e0 = __expf(v0 - m), e1 = __expf(v1 - m), e2 = __expf(v2 - m),
              e3 = __expf(v3 - m), e4 = __expf(v4 - m);
        float s = ((e0 + e1) + (e2 + e3)) + e4;
        s += __shfl_xor(s, 32); s += __shfl_xor(s, 16); s += __shfl_xor(s, 8);
        s += __shfl_xor(s, 4);  s += __shfl_xor(s, 2);  s += __shfl_xor(s, 1);
        const float inv = 1.0f / s;
        e0 *= inv; e1 *= inv; e2 *= inv; e3 *= inv; e4 *= inv;

        // P fp16 (swizzled chunks, rows padded to 320 halves)
        const int fq = (q + (q >> 3)) & 7;
        _Float16* Prow = Pl + q * 320;
        Prow[((((lane      ) >> 3) ^ fq) << 3) + (lane & 7)] = (_Float16)e0;
        Prow[((((lane +  64) >> 3) ^ fq) << 3) + (lane & 7)] = (_Float16)e1;
        Prow[((((lane + 128) >> 3) ^ fq) << 3) + (lane & 7)] = (_Float16)e2;
        Prow[((((lane + 192) >> 3) ^ fq) << 3) + (lane & 7)] = (_Float16)e3;
        if (lane < 16) {
            Prow[((((lane + 256) >> 3) ^ fq) << 3) + (lane & 7)] = (_Float16)e4;
            Prow[((((lane + 272) >> 3) ^ fq) << 3) + (lane & 7)] = (_Float16)0.f;
        }

        // band attn values only (zeros written by zfill_attn)
        float* arow = attn + ((size_t)(b * NH + h) * SQ + i0 + q) * SQ;
        const int g0 = wo + lane;
        if ((unsigned)(g0      ) < (unsigned)SQ) arow[g0      ] = e0;
        if ((unsigned)(g0 +  64) < (unsigned)SQ) arow[g0 +  64] = e1;
        if ((unsigned)(g0 + 128) < (unsigned)SQ) arow[g0 + 128] = e2;
        if ((unsigned)(g0 + 192) < (unsigned)SQ) arow[g0 + 192] = e3;
        if (lane < 16 && (unsigned)(g0 + 256) < (unsigned)SQ) arow[g0 + 256] = e4;
    }
    __syncthreads();                      // Vt + P complete

    // ---- phase 7: PV (wave w -> d-tile w) ----
    {
        const int rowp = lane & 15;                        // q (A rows)
        const int fp = (rowp + (rowp >> 3)) & 7;
        const int rowv = w * 16 + (lane & 15);             // d (B rows)
        const int fv = (rowv + (rowv >> 3)) & 7;
        floatx4 acc = (floatx4){0.f, 0.f, 0.f, 0.f};
#pragma unroll
        for (int ks = 0; ks < 9; ++ks) {
            const int lch = ks * 4 + (lane >> 4);          // logical chunk 0..35
            half8 ap = *(const half8*)(Pl + rowp * 320 + ((lch ^ fp) << 3));
            half8 bp = *(const half8*)(KV + rowv * 320 + ((lch ^ fv) << 3));
            acc = __builtin_amdgcn_mfma_f32_16x16x32_f16(ap, bp, acc, 0, 0, 0);
        }
        const int dcol = w * 16 + (lane & 15);
#pragma unroll
        for (int r = 0; r < 4; ++r) {
            const int q = ((lane >> 4) << 2) + r;
            ctx[((size_t)(b * SQ + i0 + q)) * DM + h * DH + dcol] = (_Float16)acc[r];
        }
    }
}

// ---------------------------------------------------------------------------
extern "C" void kernel_launch(void* const* d_in, const int* in_sizes, int n_in,
                              void* d_out, int out_size, void* d_ws, size_t ws_size,
                              hipStream_t stream)
{
    const float* x  = (const float*)d_in[0];
    const float* Wq = (const float*)d_in[1];
    const float* bq = (const float*)d_in[2];
    const float* Wk = (const float*)d_in[3];
    const float* bk = (const float*)d_in[4];
    const float* Wv = (const float*)d_in[5];
    const float* bv = (const float*)d_in[6];
    const float* Wo = (const float*)d_in[7];
    const float* bo = (const float*)d_in[8];

    float* out  = (float*)d_out;
    float* attn = out + (size_t)NB * SQ * DM;

    const size_t tok = (size_t)NB * SQ * DM;   // 4,194,304
    const size_t wsz = (size_t)DM * DM;        // 1,048,576

    _Float16* xh   = (_Float16*)d_ws;
    _Float16* Wqh  = xh   + tok;
    _Float16* Wkh  = Wqh  + wsz;
    _Float16* Wvh  = Wkh  + wsz;
    _Float16* Woh  = Wvh  + wsz;
    _Float16* Qh   = Woh  + wsz;
    _Float16* Kh   = Qh   + tok;
    _Float16* Vh   = Kh   + tok;
    _Float16* ctxh = Vh   + tok;               // total ~50 MB fp16

    // 0) zero-fill out-of-band attn region (pure streaming store kernel;
    //    its L2->HBM drain overlaps the compute kernels that follow)
    zfill_attn<<<dim3(2048), dim3(256), 0, stream>>>((float4*)attn);

    // 1) fp32 -> fp16 converts (single fused launch)
    cvt5<<<dim3((int)(tok / 8 / 256), 5), dim3(256), 0, stream>>>(
        x, Wq, Wk, Wv, Wo, xh, Wqh, Wkh, Wvh, Woh,
        (int)(tok / 8), (int)(wsz / 8));

    // 2) QKV projections (fp16 MFMA, fused via grid.z, fp16 out in [B,S,D])
    gemm_h<1, 128><<<dim3(DM / 128, (NB * SQ) / 128, 3), dim3(256), 0, stream>>>(
        xh, Wqh, Wkh, Wvh, bq, bk, bv, Qh, Kh, Vh);

    // 3) banded attention: MFMA QK^T + softmax + band writes + MFMA PV
    attn_mfma<<<dim3(SQ / 16, NH, NB), dim3(256), 0, stream>>>(Qh, Kh, Vh, attn, ctxh);

    // 4) output projection (fp16 MFMA, fp32 out; BN=64 -> 512 blocks, 2+/CU)
    gemm_h<0, 64><<<dim3(DM / 64, (NB * SQ) / 128, 1), dim3(256), 0, stream>>>(
        ctxh, Woh, Woh, Woh, bo, bo, bo, out, out, out);
}

// Round 9
// 637.496 us; speedup vs baseline: 1.1054x; 1.1054x over previous
//
#include <hip/hip_runtime.h>
#include <cstddef>

#define NB 2
#define NH 16
#define SQ 2048
#define DM 1024
#define DH 64
#define WN 128

using half8  = __attribute__((ext_vector_type(8))) _Float16;
using half4  = __attribute__((ext_vector_type(4))) _Float16;
using floatx4 = __attribute__((ext_vector_type(4))) float;

__device__ __forceinline__ void gl_lds16(const _Float16* g, _Float16* l) {
    __builtin_amdgcn_global_load_lds(
        (const __attribute__((address_space(1))) void*)g,
        (__attribute__((address_space(3))) void*)l, 16, 0, 0);
}

// ---------------------------------------------------------------------------
// fp32 -> fp16 converter, fused: y=0 -> x tensor, y=1..4 -> the 4 weights.
// ---------------------------------------------------------------------------
__global__ __launch_bounds__(256) void cvt5(
    const float* __restrict__ sx,
    const float* __restrict__ s1, const float* __restrict__ s2,
    const float* __restrict__ s3, const float* __restrict__ s4,
    _Float16* __restrict__ dx,
    _Float16* __restrict__ d1, _Float16* __restrict__ d2,
    _Float16* __restrict__ d3, _Float16* __restrict__ d4,
    int n8x, int n8w)
{
    const int y = blockIdx.y;
    const float* s = (y == 0) ? sx : (y == 1) ? s1 : (y == 2) ? s2
                   : (y == 3) ? s3 : s4;
    _Float16*   d = (y == 0) ? dx : (y == 1) ? d1 : (y == 2) ? d2
                   : (y == 3) ? d3 : d4;
    const int n8 = (y == 0) ? n8x : n8w;
    int idx = blockIdx.x * 256 + threadIdx.x;
    if (idx < n8) {
        const float4 a = ((const float4*)s)[idx * 2];
        const float4 b = ((const float4*)s)[idx * 2 + 1];
        half8 h;
        h[0] = (_Float16)a.x; h[1] = (_Float16)a.y;
        h[2] = (_Float16)a.z; h[3] = (_Float16)a.w;
        h[4] = (_Float16)b.x; h[5] = (_Float16)b.y;
        h[6] = (_Float16)b.z; h[7] = (_Float16)b.w;
        ((half8*)d)[idx] = h;
    }
}

// ---------------------------------------------------------------------------
// fp16 MFMA GEMM (m97 structure): C = A @ W^T + bias.
// BN = output-tile width (128 for QKV; 64 for out-proj -> 512 blocks, 2+/CU).
// ---------------------------------------------------------------------------
template <int OUT_HALF, int BN>
__global__ __launch_bounds__(256) void gemm_h(
    const _Float16* __restrict__ A,
    const _Float16* __restrict__ W0, const _Float16* __restrict__ W1,
    const _Float16* __restrict__ W2,
    const float* __restrict__ b0, const float* __restrict__ b1,
    const float* __restrict__ b2,
    void* __restrict__ O0, void* __restrict__ O1, void* __restrict__ O2)
{
    constexpr int K = DM, N = DM, BK = 64;
    constexpr int NF = BN / 32;          // n-frags per wave (4 or 2)

    const _Float16* Wp = (blockIdx.z == 0) ? W0 : (blockIdx.z == 1) ? W1 : W2;
    const float*    bb = (blockIdx.z == 0) ? b0 : (blockIdx.z == 1) ? b1 : b2;
    void*           Op = (blockIdx.z == 0) ? O0 : (blockIdx.z == 1) ? O1 : O2;

    __shared__ _Float16 Asl[128 * BK];   // 16 KB
    __shared__ _Float16 Bsl[BN * BK];    // 16 or 8 KB

    const int tid  = threadIdx.x;
    const int lane = tid & 63;
    const int w    = tid >> 6;          // wave 0..3
    const int wm   = w & 1, wn = w >> 1;
    const int m0   = blockIdx.y * 128;
    const int n0   = blockIdx.x * BN;

    const int l8 = lane >> 3;           // row within 8-row group
    const int lc = lane & 7;            // 16B chunk within row

    floatx4 acc[4][NF];
#pragma unroll
    for (int t = 0; t < 4; ++t)
#pragma unroll
        for (int u = 0; u < NF; ++u) acc[t][u] = (floatx4){0.f, 0.f, 0.f, 0.f};

    for (int k0 = 0; k0 < K; k0 += BK) {
        __syncthreads();                 // prior iter's LDS reads done
#pragma unroll
        for (int i = 0; i < 4; ++i) {    // A rows 0..127
            const int r  = w * 8 + l8 + i * 32;
            const int ca = lc ^ (r & 7);             // swizzled chunk
            gl_lds16(A + (size_t)(m0 + r) * K + k0 + ca * 8,
                     Asl + r * BK + lc * 8);
        }
#pragma unroll
        for (int i = 0; i < BN / 32; ++i) {          // B rows 0..BN-1
            const int r  = w * 8 + l8 + i * 32;
            const int ca = lc ^ (r & 7);
            gl_lds16(Wp + (size_t)(n0 + r) * K + k0 + ca * 8,
                     Bsl + r * BK + lc * 8);
        }
        __syncthreads();                 // drain global_load_lds
#pragma unroll
        for (int kk = 0; kk < BK; kk += 32) {
            half8 af[4], bf[NF];
            const int q = (kk >> 3) + (lane >> 4);   // chunk idx 0..7
#pragma unroll
            for (int t = 0; t < 4; ++t) {
                const int ra = wm * 64 + t * 16 + (lane & 15);
                af[t] = *(const half8*)(Asl + ra * BK + ((q ^ (ra & 7)) << 3));
            }
#pragma unroll
            for (int u = 0; u < NF; ++u) {
                const int rb = wn * (BN / 2) + u * 16 + (lane & 15);
                bf[u] = *(const half8*)(Bsl + rb * BK + ((q ^ (rb & 7)) << 3));
            }
#pragma unroll
            for (int t = 0; t < 4; ++t)
#pragma unroll
                for (int u = 0; u < NF; ++u)
                    acc[t][u] = __builtin_amdgcn_mfma_f32_16x16x32_f16(
                        af[t], bf[u], acc[t][u], 0, 0, 0);
        }
    }

    // epilogue: C/D layout col=lane&15, row=(lane>>4)*4+reg
    const int col0 = n0 + wn * (BN / 2) + (lane & 15);
    const int row0 = m0 + wm * 64 + ((lane >> 4) << 2);
#pragma unroll
    for (int u = 0; u < NF; ++u) {
        const int n = col0 + u * 16;
        const float bias = bb[n];
#pragma unroll
        for (int t = 0; t < 4; ++t) {
            const int m = row0 + t * 16;
#pragma unroll
            for (int r = 0; r < 4; ++r) {
                const float v = acc[t][u][r] + bias;
                if (OUT_HALF)
                    ((_Float16*)Op)[(size_t)(m + r) * N + n] = (_Float16)v;
                else
                    ((float*)Op)[(size_t)(m + r) * N + n] = v;
            }
        }
    }
}

// ---------------------------------------------------------------------------
// Sliding-window attention v9: v5 core (measured best) with NON-TEMPORAL
// stores for the attn-probability output (band + zeros). The attn buffer is
// write-once/never-read -> nt stores keep the 537 MB stream from evicting
// the K/V working set (~32 MB, re-read ~17x by overlapping windows) out of
// L2. ctx stays cacheable (read 16x by the out-projection).
// (fix vs R8: nt-store the zeros via the clang ext-vector floatx4 type —
//  __builtin_nontemporal_store rejects HIP_vector_type float4.)
// ---------------------------------------------------------------------------
__global__ __launch_bounds__(256) void attn_mfma(
    const _Float16* __restrict__ Q, const _Float16* __restrict__ K,
    const _Float16* __restrict__ V, float* __restrict__ attn,
    _Float16* __restrict__ ctx)
{
    const int tid  = threadIdx.x;
    const int lane = tid & 63;
    const int w    = tid >> 6;            // wave 0..3
    const int h = blockIdx.y, b = blockIdx.z;
    const int i0 = blockIdx.x * 16;
    const int wo = i0 - WN;               // window origin (multiple of 16)

    __shared__ _Float16 KV[64 * 320];     // 40 KB: K[272][64] then Vt[64][320]
    __shared__ _Float16 Qs[16 * 64];      // 2 KB
    __shared__ float    Sl[16 * 276];     // 17.25 KB (276: 2-way-free stride)
    __shared__ _Float16 Pl[16 * 320];     // 10 KB

    const int l8 = lane >> 3;             // row in 8-row stage group
    const int lc = lane & 7;              // 16B chunk in row

    // ---- phase 1: stage K rows 0..255 (all waves) ----
#pragma unroll
    for (int i = 0; i < 8; ++i) {
        const int r  = w * 8 + l8 + i * 32;
        const int jg = wo + r;
        const int jc = jg < 0 ? 0 : (jg >= SQ ? SQ - 1 : jg);
        const int ca = lc ^ (r & 7);
        gl_lds16(K + ((size_t)(b * SQ + jc)) * DM + h * DH + ca * 8,
                 KV + r * 64 + lc * 8);
    }
    if (w < 2) {                          // K rows 256..271
        const int r  = 256 + w * 8 + l8;
        const int jg = wo + r;
        const int jc = jg >= SQ ? SQ - 1 : jg;
        const int ca = lc ^ (r & 7);
        gl_lds16(K + ((size_t)(b * SQ + jc)) * DM + h * DH + ca * 8,
                 KV + r * 64 + lc * 8);
    } else {                              // Q rows 0..15 (waves 2,3)
        const int r  = (w - 2) * 8 + l8;
        const int ca = lc ^ (r & 7);
        gl_lds16(Q + ((size_t)(b * SQ + i0 + r)) * DM + h * DH + ca * 8,
                 Qs + r * 64 + lc * 8);
    }

    // V window -> registers (288 rows x 8 chunks = 9 tasks/thread exactly)
    half8 vr[9];
#pragma unroll
    for (int it = 0; it < 9; ++it) {
        const int idx = tid + 256 * it;
        const int j = idx >> 3, c8 = idx & 7;
        const int jg = wo + j;
        const int jc = jg < 0 ? 0 : (jg >= SQ ? SQ - 1 : jg);
        vr[it] = *(const half8*)(V + ((size_t)(b * SQ + jc)) * DM + h * DH + c8 * 8);
    }

    __syncthreads();                      // K/Q staged (drains vmcnt)

    // ---- phase 3: QK^T ----
    half8 af0, af1;
    {
        const int row = lane & 15;
        af0 = *(const half8*)(Qs + row * 64 + ((((lane >> 4))     ^ (row & 7)) << 3));
        af1 = *(const half8*)(Qs + row * 64 + (((4 + (lane >> 4)) ^ (row & 7)) << 3));
    }
    for (int t = w; t < 17; t += 4) {
        const int rb = t * 16 + (lane & 15);
        half8 bf0 = *(const half8*)(KV + rb * 64 + ((((lane >> 4))     ^ (rb & 7)) << 3));
        half8 bf1 = *(const half8*)(KV + rb * 64 + (((4 + (lane >> 4)) ^ (rb & 7)) << 3));
        floatx4 acc = (floatx4){0.f, 0.f, 0.f, 0.f};
        acc = __builtin_amdgcn_mfma_f32_16x16x32_f16(af0, bf0, acc, 0, 0, 0);
        acc = __builtin_amdgcn_mfma_f32_16x16x32_f16(af1, bf1, acc, 0, 0, 0);
        const int jloc = t * 16 + (lane & 15);
        const int jg   = wo + jloc;
        const bool inr = (jg >= 0) && (jg < SQ);
#pragma unroll
        for (int r = 0; r < 4; ++r) {
            const int q = ((lane >> 4) << 2) + r;
            const bool valid = ((unsigned)(jloc - q) <= 256u) && inr;
            Sl[q * 276 + jloc] = valid ? acc[r] * 0.125f : -1e30f;
        }
    }
    __syncthreads();                      // S complete, K reads done

    // ---- phase 5a: scatter V^T into KV (K buffer dead) ----
#pragma unroll
    for (int it = 0; it < 9; ++it) {
        const int idx = tid + 256 * it;
        const int j = idx >> 3, c8 = idx & 7;
        const int jc3 = j >> 3, jl = j & 7;
#pragma unroll
        for (int e = 0; e < 8; ++e) {
            const int d = c8 * 8 + e;     // d>>3 == c8, f(d) = (c8+e)&7
            KV[d * 320 + ((jc3 ^ ((c8 + e) & 7)) << 3) + jl] = vr[it][e];
        }
    }

    // ---- phase 5b: softmax + P fp16 + full attn rows (nt stores) ----
    for (int q = w; q < 16; q += 4) {
        const float* Srow = Sl + q * 276;
        const float v0 = Srow[lane];
        const float v1 = Srow[lane + 64];
        const float v2 = Srow[lane + 128];
        const float v3 = Srow[lane + 192];
        const float v4 = (lane < 16) ? Srow[lane + 256] : -1e30f;
        float m = fmaxf(fmaxf(fmaxf(v0, v1), fmaxf(v2, v3)), v4);
        m = fmaxf(m, __shfl_xor(m, 32));
        m = fmaxf(m, __shfl_xor(m, 16));
        m = fmaxf(m, __shfl_xor(m, 8));
        m = fmaxf(m, __shfl_xor(m, 4));
        m = fmaxf(m, __shfl_xor(m, 2));
        m = fmaxf(m, __shfl_xor(m, 1));
        float e0 = __expf(v0 - m), e1 = __expf(v1 - m), e2 = __expf(v2 - m),
              e3 = __expf(v3 - m), e4 = __expf(v4 - m);
        float s = ((e0 + e1) + (e2 + e3)) + e4;
        s += __shfl_xor(s, 32); s += __shfl_xor(s, 16); s += __shfl_xor(s, 8);
        s += __shfl_xor(s, 4);  s += __shfl_xor(s, 2);  s += __shfl_xor(s, 1);
        const float inv = 1.0f / s;
        e0 *= inv; e1 *= inv; e2 *= inv; e3 *= inv; e4 *= inv;

        // P fp16 (swizzled chunks, rows padded to 320 halves)
        const int fq = (q + (q >> 3)) & 7;
        _Float16* Prow = Pl + q * 320;
        Prow[((((lane      ) >> 3) ^ fq) << 3) + (lane & 7)] = (_Float16)e0;
        Prow[((((lane +  64) >> 3) ^ fq) << 3) + (lane & 7)] = (_Float16)e1;
        Prow[((((lane + 128) >> 3) ^ fq) << 3) + (lane & 7)] = (_Float16)e2;
        Prow[((((lane + 192) >> 3) ^ fq) << 3) + (lane & 7)] = (_Float16)e3;
        if (lane < 16) {
            Prow[((((lane + 256) >> 3) ^ fq) << 3) + (lane & 7)] = (_Float16)e4;
            Prow[((((lane + 272) >> 3) ^ fq) << 3) + (lane & 7)] = (_Float16)0.f;
        }

        // full attn row: band values + float4 zeros — all non-temporal
        float* arow = attn + ((size_t)(b * NH + h) * SQ + i0 + q) * SQ;
        const int g0 = wo + lane;
        if ((unsigned)(g0      ) < (unsigned)SQ)
            __builtin_nontemporal_store(e0, arow + g0);
        if ((unsigned)(g0 +  64) < (unsigned)SQ)
            __builtin_nontemporal_store(e1, arow + g0 + 64);
        if ((unsigned)(g0 + 128) < (unsigned)SQ)
            __builtin_nontemporal_store(e2, arow + g0 + 128);
        if ((unsigned)(g0 + 192) < (unsigned)SQ)
            __builtin_nontemporal_store(e3, arow + g0 + 192);
        if (lane < 16 && (unsigned)(g0 + 256) < (unsigned)SQ)
            __builtin_nontemporal_store(e4, arow + g0 + 256);
        const int a0 = wo > 0 ? wo : 0;
        const int b0 = (wo + 272 < SQ) ? (wo + 272) : SQ;
        const floatx4 zv = (floatx4){0.f, 0.f, 0.f, 0.f};
        floatx4* za = (floatx4*)arow;
        const int na = a0 >> 2;
        for (int c = lane; c < na; c += 64)
            __builtin_nontemporal_store(zv, za + c);
        floatx4* zb = (floatx4*)(arow + b0);
        const int nb = (SQ - b0) >> 2;
        for (int c = lane; c < nb; c += 64)
            __builtin_nontemporal_store(zv, zb + c);
    }
    __syncthreads();                      // Vt + P complete

    // ---- phase 7: PV (wave w -> d-tile w) ----
    {
        const int rowp = lane & 15;                        // q (A rows)
        const int fp = (rowp + (rowp >> 3)) & 7;
        const int rowv = w * 16 + (lane & 15);             // d (B rows)
        const int fv = (rowv + (rowv >> 3)) & 7;
        floatx4 acc = (floatx4){0.f, 0.f, 0.f, 0.f};
#pragma unroll
        for (int ks = 0; ks < 9; ++ks) {
            const int lch = ks * 4 + (lane >> 4);          // logical chunk 0..35
            half8 ap = *(const half8*)(Pl + rowp * 320 + ((lch ^ fp) << 3));
            half8 bp = *(const half8*)(KV + rowv * 320 + ((lch ^ fv) << 3));
            acc = __builtin_amdgcn_mfma_f32_16x16x32_f16(ap, bp, acc, 0, 0, 0);
        }
        const int dcol = w * 16 + (lane & 15);
#pragma unroll
        for (int r = 0; r < 4; ++r) {
            const int q = ((lane >> 4) << 2) + r;
            ctx[((size_t)(b * SQ + i0 + q)) * DM + h * DH + dcol] = (_Float16)acc[r];
        }
    }
}

// ---------------------------------------------------------------------------
extern "C" void kernel_launch(void* const* d_in, const int* in_sizes, int n_in,
                              void* d_out, int out_size, void* d_ws, size_t ws_size,
                              hipStream_t stream)
{
    const float* x  = (const float*)d_in[0];
    const float* Wq = (const float*)d_in[1];
    const float* bq = (const float*)d_in[2];
    const float* Wk = (const float*)d_in[3];
    const float* bk = (const float*)d_in[4];
    const float* Wv = (const float*)d_in[5];
    const float* bv = (const float*)d_in[6];
    const float* Wo = (const float*)d_in[7];
    const float* bo = (const float*)d_in[8];

    float* out  = (float*)d_out;
    float* attn = out + (size_t)NB * SQ * DM;

    const size_t tok = (size_t)NB * SQ * DM;   // 4,194,304
    const size_t wsz = (size_t)DM * DM;        // 1,048,576

    _Float16* xh   = (_Float16*)d_ws;
    _Float16* Wqh  = xh   + tok;
    _Float16* Wkh  = Wqh  + wsz;
    _Float16* Wvh  = Wkh  + wsz;
    _Float16* Woh  = Wvh  + wsz;
    _Float16* Qh   = Woh  + wsz;
    _Float16* Kh   = Qh   + tok;
    _Float16* Vh   = Kh   + tok;
    _Float16* ctxh = Vh   + tok;               // total ~50 MB fp16

    // 1) fp32 -> fp16 converts (single fused launch)
    cvt5<<<dim3((int)(tok / 8 / 256), 5), dim3(256), 0, stream>>>(
        x, Wq, Wk, Wv, Wo, xh, Wqh, Wkh, Wvh, Woh,
        (int)(tok / 8), (int)(wsz / 8));

    // 2) QKV projections (fp16 MFMA, fused via grid.z, fp16 out in [B,S,D])
    gemm_h<1, 128><<<dim3(DM / 128, (NB * SQ) / 128, 3), dim3(256), 0, stream>>>(
        xh, Wqh, Wkh, Wvh, bq, bk, bv, Qh, Kh, Vh);

    // 3) banded attention: MFMA QK^T + softmax + full attn rows + MFMA PV
    attn_mfma<<<dim3(SQ / 16, NH, NB), dim3(256), 0, stream>>>(Qh, Kh, Vh, attn, ctxh);

    // 4) output projection (fp16 MFMA, fp32 out; BN=64 -> 512 blocks, 2+/CU)
    gemm_h<0, 64><<<dim3(DM / 64, (NB * SQ) / 128, 1), dim3(256), 0, stream>>>(
        ctxh, Woh, Woh, Woh, bo, bo, bo, out, out, out);
}

// Round 10
// 634.826 us; speedup vs baseline: 1.1101x; 1.0042x over previous
//
#include <hip/hip_runtime.h>
#include <cstddef>

#define NB 2
#define NH 16
#define SQ 2048
#define DM 1024
#define DH 64
#define WN 128

using half8  = __attribute__((ext_vector_type(8))) _Float16;
using half4  = __attribute__((ext_vector_type(4))) _Float16;
using floatx4 = __attribute__((ext_vector_type(4))) float;

__device__ __forceinline__ void gl_lds16(const _Float16* g, _Float16* l) {
    __builtin_amdgcn_global_load_lds(
        (const __attribute__((address_space(1))) void*)g,
        (__attribute__((address_space(3))) void*)l, 16, 0, 0);
}

// ---------------------------------------------------------------------------
// fp32 -> fp16 converter, fused: y=0 -> x tensor, y=1..4 -> the 4 weights.
// ---------------------------------------------------------------------------
__global__ __launch_bounds__(256) void cvt5(
    const float* __restrict__ sx,
    const float* __restrict__ s1, const float* __restrict__ s2,
    const float* __restrict__ s3, const float* __restrict__ s4,
    _Float16* __restrict__ dx,
    _Float16* __restrict__ d1, _Float16* __restrict__ d2,
    _Float16* __restrict__ d3, _Float16* __restrict__ d4,
    int n8x, int n8w)
{
    const int y = blockIdx.y;
    const float* s = (y == 0) ? sx : (y == 1) ? s1 : (y == 2) ? s2
                   : (y == 3) ? s3 : s4;
    _Float16*   d = (y == 0) ? dx : (y == 1) ? d1 : (y == 2) ? d2
                   : (y == 3) ? d3 : d4;
    const int n8 = (y == 0) ? n8x : n8w;
    int idx = blockIdx.x * 256 + threadIdx.x;
    if (idx < n8) {
        const float4 a = ((const float4*)s)[idx * 2];
        const float4 b = ((const float4*)s)[idx * 2 + 1];
        half8 h;
        h[0] = (_Float16)a.x; h[1] = (_Float16)a.y;
        h[2] = (_Float16)a.z; h[3] = (_Float16)a.w;
        h[4] = (_Float16)b.x; h[5] = (_Float16)b.y;
        h[6] = (_Float16)b.z; h[7] = (_Float16)b.w;
        ((half8*)d)[idx] = h;
    }
}

// ---------------------------------------------------------------------------
// fp16 MFMA GEMM (m97 structure): C = A @ W^T + bias.
// BN = output-tile width (128 for QKV; 64 for out-proj -> 512 blocks, 2+/CU).
// ---------------------------------------------------------------------------
template <int OUT_HALF, int BN>
__global__ __launch_bounds__(256) void gemm_h(
    const _Float16* __restrict__ A,
    const _Float16* __restrict__ W0, const _Float16* __restrict__ W1,
    const _Float16* __restrict__ W2,
    const float* __restrict__ b0, const float* __restrict__ b1,
    const float* __restrict__ b2,
    void* __restrict__ O0, void* __restrict__ O1, void* __restrict__ O2)
{
    constexpr int K = DM, N = DM, BK = 64;
    constexpr int NF = BN / 32;          // n-frags per wave (4 or 2)

    const _Float16* Wp = (blockIdx.z == 0) ? W0 : (blockIdx.z == 1) ? W1 : W2;
    const float*    bb = (blockIdx.z == 0) ? b0 : (blockIdx.z == 1) ? b1 : b2;
    void*           Op = (blockIdx.z == 0) ? O0 : (blockIdx.z == 1) ? O1 : O2;

    __shared__ _Float16 Asl[128 * BK];   // 16 KB
    __shared__ _Float16 Bsl[BN * BK];    // 16 or 8 KB

    const int tid  = threadIdx.x;
    const int lane = tid & 63;
    const int w    = tid >> 6;          // wave 0..3
    const int wm   = w & 1, wn = w >> 1;
    const int m0   = blockIdx.y * 128;
    const int n0   = blockIdx.x * BN;

    const int l8 = lane >> 3;           // row within 8-row group
    const int lc = lane & 7;            // 16B chunk within row

    floatx4 acc[4][NF];
#pragma unroll
    for (int t = 0; t < 4; ++t)
#pragma unroll
        for (int u = 0; u < NF; ++u) acc[t][u] = (floatx4){0.f, 0.f, 0.f, 0.f};

    for (int k0 = 0; k0 < K; k0 += BK) {
        __syncthreads();                 // prior iter's LDS reads done
#pragma unroll
        for (int i = 0; i < 4; ++i) {    // A rows 0..127
            const int r  = w * 8 + l8 + i * 32;
            const int ca = lc ^ (r & 7);             // swizzled chunk
            gl_lds16(A + (size_t)(m0 + r) * K + k0 + ca * 8,
                     Asl + r * BK + lc * 8);
        }
#pragma unroll
        for (int i = 0; i < BN / 32; ++i) {          // B rows 0..BN-1
            const int r  = w * 8 + l8 + i * 32;
            const int ca = lc ^ (r & 7);
            gl_lds16(Wp + (size_t)(n0 + r) * K + k0 + ca * 8,
                     Bsl + r * BK + lc * 8);
        }
        __syncthreads();                 // drain global_load_lds
#pragma unroll
        for (int kk = 0; kk < BK; kk += 32) {
            half8 af[4], bf[NF];
            const int q = (kk >> 3) + (lane >> 4);   // chunk idx 0..7
#pragma unroll
            for (int t = 0; t < 4; ++t) {
                const int ra = wm * 64 + t * 16 + (lane & 15);
                af[t] = *(const half8*)(Asl + ra * BK + ((q ^ (ra & 7)) << 3));
            }
#pragma unroll
            for (int u = 0; u < NF; ++u) {
                const int rb = wn * (BN / 2) + u * 16 + (lane & 15);
                bf[u] = *(const half8*)(Bsl + rb * BK + ((q ^ (rb & 7)) << 3));
            }
#pragma unroll
            for (int t = 0; t < 4; ++t)
#pragma unroll
                for (int u = 0; u < NF; ++u)
                    acc[t][u] = __builtin_amdgcn_mfma_f32_16x16x32_f16(
                        af[t], bf[u], acc[t][u], 0, 0, 0);
        }
    }

    // epilogue: C/D layout col=lane&15, row=(lane>>4)*4+reg
    const int col0 = n0 + wn * (BN / 2) + (lane & 15);
    const int row0 = m0 + wm * 64 + ((lane >> 4) << 2);
#pragma unroll
    for (int u = 0; u < NF; ++u) {
        const int n = col0 + u * 16;
        const float bias = bb[n];
#pragma unroll
        for (int t = 0; t < 4; ++t) {
            const int m = row0 + t * 16;
#pragma unroll
            for (int r = 0; r < 4; ++r) {
                const float v = acc[t][u][r] + bias;
                if (OUT_HALF)
                    ((_Float16*)Op)[(size_t)(m + r) * N + n] = (_Float16)v;
                else
                    ((float*)Op)[(size_t)(m + r) * N + n] = v;
            }
        }
    }
}

// ---------------------------------------------------------------------------
// Sliding-window attention v10: v9 (nt stores, measured best) + bijective
// XCD-chunk swizzle. Default round-robin dispatch spreads the 4096 tiles
// over 8 XCDs so each XCD touches all 32 (b,h) heads (~64 MB working set vs
// 4 MB L2). Chunked remap gives each XCD 512 contiguous tiles = 4 whole
// heads -> K+V per XCD = 2 MB < 4 MB L2; neighboring tiles (94% window
// overlap) share an L2. 4096 % 8 == 0 -> bijective.
// ---------------------------------------------------------------------------
__global__ __launch_bounds__(256) void attn_mfma(
    const _Float16* __restrict__ Q, const _Float16* __restrict__ K,
    const _Float16* __restrict__ V, float* __restrict__ attn,
    _Float16* __restrict__ ctx)
{
    const int tid  = threadIdx.x;
    const int lane = tid & 63;
    const int w    = tid >> 6;            // wave 0..3

    // XCD-chunk swizzle (T1)
    const int f    = blockIdx.x + 128 * (blockIdx.y + 16 * blockIdx.z);
    const int newf = (f & 7) * 512 + (f >> 3);
    const int qt   = newf & 127;
    const int h    = (newf >> 7) & 15;
    const int b    = newf >> 11;

    const int i0 = qt * 16;
    const int wo = i0 - WN;               // window origin (multiple of 16)

    __shared__ _Float16 KV[64 * 320];     // 40 KB: K[272][64] then Vt[64][320]
    __shared__ _Float16 Qs[16 * 64];      // 2 KB
    __shared__ float    Sl[16 * 276];     // 17.25 KB (276: 2-way-free stride)
    __shared__ _Float16 Pl[16 * 320];     // 10 KB

    const int l8 = lane >> 3;             // row in 8-row stage group
    const int lc = lane & 7;              // 16B chunk in row

    // ---- phase 1: stage K rows 0..255 (all waves) ----
#pragma unroll
    for (int i = 0; i < 8; ++i) {
        const int r  = w * 8 + l8 + i * 32;
        const int jg = wo + r;
        const int jc = jg < 0 ? 0 : (jg >= SQ ? SQ - 1 : jg);
        const int ca = lc ^ (r & 7);
        gl_lds16(K + ((size_t)(b * SQ + jc)) * DM + h * DH + ca * 8,
                 KV + r * 64 + lc * 8);
    }
    if (w < 2) {                          // K rows 256..271
        const int r  = 256 + w * 8 + l8;
        const int jg = wo + r;
        const int jc = jg >= SQ ? SQ - 1 : jg;
        const int ca = lc ^ (r & 7);
        gl_lds16(K + ((size_t)(b * SQ + jc)) * DM + h * DH + ca * 8,
                 KV + r * 64 + lc * 8);
    } else {                              // Q rows 0..15 (waves 2,3)
        const int r  = (w - 2) * 8 + l8;
        const int ca = lc ^ (r & 7);
        gl_lds16(Q + ((size_t)(b * SQ + i0 + r)) * DM + h * DH + ca * 8,
                 Qs + r * 64 + lc * 8);
    }

    // V window -> registers (288 rows x 8 chunks = 9 tasks/thread exactly)
    half8 vr[9];
#pragma unroll
    for (int it = 0; it < 9; ++it) {
        const int idx = tid + 256 * it;
        const int j = idx >> 3, c8 = idx & 7;
        const int jg = wo + j;
        const int jc = jg < 0 ? 0 : (jg >= SQ ? SQ - 1 : jg);
        vr[it] = *(const half8*)(V + ((size_t)(b * SQ + jc)) * DM + h * DH + c8 * 8);
    }

    __syncthreads();                      // K/Q staged (drains vmcnt)

    // ---- phase 3: QK^T ----
    half8 af0, af1;
    {
        const int row = lane & 15;
        af0 = *(const half8*)(Qs + row * 64 + ((((lane >> 4))     ^ (row & 7)) << 3));
        af1 = *(const half8*)(Qs + row * 64 + (((4 + (lane >> 4)) ^ (row & 7)) << 3));
    }
    for (int t = w; t < 17; t += 4) {
        const int rb = t * 16 + (lane & 15);
        half8 bf0 = *(const half8*)(KV + rb * 64 + ((((lane >> 4))     ^ (rb & 7)) << 3));
        half8 bf1 = *(const half8*)(KV + rb * 64 + (((4 + (lane >> 4)) ^ (rb & 7)) << 3));
        floatx4 acc = (floatx4){0.f, 0.f, 0.f, 0.f};
        acc = __builtin_amdgcn_mfma_f32_16x16x32_f16(af0, bf0, acc, 0, 0, 0);
        acc = __builtin_amdgcn_mfma_f32_16x16x32_f16(af1, bf1, acc, 0, 0, 0);
        const int jloc = t * 16 + (lane & 15);
        const int jg   = wo + jloc;
        const bool inr = (jg >= 0) && (jg < SQ);
#pragma unroll
        for (int r = 0; r < 4; ++r) {
            const int q = ((lane >> 4) << 2) + r;
            const bool valid = ((unsigned)(jloc - q) <= 256u) && inr;
            Sl[q * 276 + jloc] = valid ? acc[r] * 0.125f : -1e30f;
        }
    }
    __syncthreads();                      // S complete, K reads done

    // ---- phase 5a: scatter V^T into KV (K buffer dead) ----
#pragma unroll
    for (int it = 0; it < 9; ++it) {
        const int idx = tid + 256 * it;
        const int j = idx >> 3, c8 = idx & 7;
        const int jc3 = j >> 3, jl = j & 7;
#pragma unroll
        for (int e = 0; e < 8; ++e) {
            const int d = c8 * 8 + e;     // d>>3 == c8, f(d) = (c8+e)&7
            KV[d * 320 + ((jc3 ^ ((c8 + e) & 7)) << 3) + jl] = vr[it][e];
        }
    }

    // ---- phase 5b: softmax + P fp16 + full attn rows (nt stores) ----
    for (int q = w; q < 16; q += 4) {
        const float* Srow = Sl + q * 276;
        const float v0 = Srow[lane];
        const float v1 = Srow[lane + 64];
        const float v2 = Srow[lane + 128];
        const float v3 = Srow[lane + 192];
        const float v4 = (lane < 16) ? Srow[lane + 256] : -1e30f;
        float m = fmaxf(fmaxf(fmaxf(v0, v1), fmaxf(v2, v3)), v4);
        m = fmaxf(m, __shfl_xor(m, 32));
        m = fmaxf(m, __shfl_xor(m, 16));
        m = fmaxf(m, __shfl_xor(m, 8));
        m = fmaxf(m, __shfl_xor(m, 4));
        m = fmaxf(m, __shfl_xor(m, 2));
        m = fmaxf(m, __shfl_xor(m, 1));
        float e0 = __expf(v0 - m), e1 = __expf(v1 - m), e2 = __expf(v2 - m),
              e3 = __expf(v3 - m), e4 = __expf(v4 - m);
        float s = ((e0 + e1) + (e2 + e3)) + e4;
        s += __shfl_xor(s, 32); s += __shfl_xor(s, 16); s += __shfl_xor(s, 8);
        s += __shfl_xor(s, 4);  s += __shfl_xor(s, 2);  s += __shfl_xor(s, 1);
        const float inv = 1.0f / s;
        e0 *= inv; e1 *= inv; e2 *= inv; e3 *= inv; e4 *= inv;

        // P fp16 (swizzled chunks, rows padded to 320 halves)
        const int fq = (q + (q >> 3)) & 7;
        _Float16* Prow = Pl + q * 320;
        Prow[((((lane      ) >> 3) ^ fq) << 3) + (lane & 7)] = (_Float16)e0;
        Prow[((((lane +  64) >> 3) ^ fq) << 3) + (lane & 7)] = (_Float16)e1;
        Prow[((((lane + 128) >> 3) ^ fq) << 3) + (lane & 7)] = (_Float16)e2;
        Prow[((((lane + 192) >> 3) ^ fq) << 3) + (lane & 7)] = (_Float16)e3;
        if (lane < 16) {
            Prow[((((lane + 256) >> 3) ^ fq) << 3) + (lane & 7)] = (_Float16)e4;
            Prow[((((lane + 272) >> 3) ^ fq) << 3) + (lane & 7)] = (_Float16)0.f;
        }

        // full attn row: band values + float4 zeros — all non-temporal
        float* arow = attn + ((size_t)(b * NH + h) * SQ + i0 + q) * SQ;
        const int g0 = wo + lane;
        if ((unsigned)(g0      ) < (unsigned)SQ)
            __builtin_nontemporal_store(e0, arow + g0);
        if ((unsigned)(g0 +  64) < (unsigned)SQ)
            __builtin_nontemporal_store(e1, arow + g0 + 64);
        if ((unsigned)(g0 + 128) < (unsigned)SQ)
            __builtin_nontemporal_store(e2, arow + g0 + 128);
        if ((unsigned)(g0 + 192) < (unsigned)SQ)
            __builtin_nontemporal_store(e3, arow + g0 + 192);
        if (lane < 16 && (unsigned)(g0 + 256) < (unsigned)SQ)
            __builtin_nontemporal_store(e4, arow + g0 + 256);
        const int a0 = wo > 0 ? wo : 0;
        const int b0 = (wo + 272 < SQ) ? (wo + 272) : SQ;
        const floatx4 zv = (floatx4){0.f, 0.f, 0.f, 0.f};
        floatx4* za = (floatx4*)arow;
        const int na = a0 >> 2;
        for (int c = lane; c < na; c += 64)
            __builtin_nontemporal_store(zv, za + c);
        floatx4* zb = (floatx4*)(arow + b0);
        const int nb = (SQ - b0) >> 2;
        for (int c = lane; c < nb; c += 64)
            __builtin_nontemporal_store(zv, zb + c);
    }
    __syncthreads();                      // Vt + P complete

    // ---- phase 7: PV (wave w -> d-tile w) ----
    {
        const int rowp = lane & 15;                        // q (A rows)
        const int fp = (rowp + (rowp >> 3)) & 7;
        const int rowv = w * 16 + (lane & 15);             // d (B rows)
        const int fv = (rowv + (rowv >> 3)) & 7;
        floatx4 acc = (floatx4){0.f, 0.f, 0.f, 0.f};
#pragma unroll
        for (int ks = 0; ks < 9; ++ks) {
            const int lch = ks * 4 + (lane >> 4);          // logical chunk 0..35
            half8 ap = *(const half8*)(Pl + rowp * 320 + ((lch ^ fp) << 3));
            half8 bp = *(const half8*)(KV + rowv * 320 + ((lch ^ fv) << 3));
            acc = __builtin_amdgcn_mfma_f32_16x16x32_f16(ap, bp, acc, 0, 0, 0);
        }
        const int dcol = w * 16 + (lane & 15);
#pragma unroll
        for (int r = 0; r < 4; ++r) {
            const int q = ((lane >> 4) << 2) + r;
            ctx[((size_t)(b * SQ + i0 + q)) * DM + h * DH + dcol] = (_Float16)acc[r];
        }
    }
}

// ---------------------------------------------------------------------------
extern "C" void kernel_launch(void* const* d_in, const int* in_sizes, int n_in,
                              void* d_out, int out_size, void* d_ws, size_t ws_size,
                              hipStream_t stream)
{
    const float* x  = (const float*)d_in[0];
    const float* Wq = (const float*)d_in[1];
    const float* bq = (const float*)d_in[2];
    const float* Wk = (const float*)d_in[3];
    const float* bk = (const float*)d_in[4];
    const float* Wv = (const float*)d_in[5];
    const float* bv = (const float*)d_in[6];
    const float* Wo = (const float*)d_in[7];
    const float* bo = (const float*)d_in[8];

    float* out  = (float*)d_out;
    float* attn = out + (size_t)NB * SQ * DM;

    const size_t tok = (size_t)NB * SQ * DM;   // 4,194,304
    const size_t wsz = (size_t)DM * DM;        // 1,048,576

    _Float16* xh   = (_Float16*)d_ws;
    _Float16* Wqh  = xh   + tok;
    _Float16* Wkh  = Wqh  + wsz;
    _Float16* Wvh  = Wkh  + wsz;
    _Float16* Woh  = Wvh  + wsz;
    _Float16* Qh   = Woh  + wsz;
    _Float16* Kh   = Qh   + tok;
    _Float16* Vh   = Kh   + tok;
    _Float16* ctxh = Vh   + tok;               // total ~50 MB fp16

    // 1) fp32 -> fp16 converts (single fused launch)
    cvt5<<<dim3((int)(tok / 8 / 256), 5), dim3(256), 0, stream>>>(
        x, Wq, Wk, Wv, Wo, xh, Wqh, Wkh, Wvh, Woh,
        (int)(tok / 8), (int)(wsz / 8));

    // 2) QKV projections (fp16 MFMA, fused via grid.z, fp16 out in [B,S,D])
    gemm_h<1, 128><<<dim3(DM / 128, (NB * SQ) / 128, 3), dim3(256), 0, stream>>>(
        xh, Wqh, Wkh, Wvh, bq, bk, bv, Qh, Kh, Vh);

    // 3) banded attention: MFMA QK^T + softmax + full attn rows + MFMA PV
    attn_mfma<<<dim3(SQ / 16, NH, NB), dim3(256), 0, stream>>>(Qh, Kh, Vh, attn, ctxh);

    // 4) output projection (fp16 MFMA, fp32 out; BN=64 -> 512 blocks, 2+/CU)
    gemm_h<0, 64><<<dim3(DM / 64, (NB * SQ) / 128, 1), dim3(256), 0, stream>>>(
        ctxh, Woh, Woh, Woh, bo, bo, bo, out, out, out);
}

// Round 11
// 634.826 us; speedup vs baseline: 1.1101x; 1.0000x over previous
//
#include <hip/hip_runtime.h>
#include <cstddef>

#define NB 2
#define NH 16
#define SQ 2048
#define DM 1024
#define DH 64
#define WN 128

using half8  = __attribute__((ext_vector_type(8))) _Float16;
using half4  = __attribute__((ext_vector_type(4))) _Float16;
using floatx4 = __attribute__((ext_vector_type(4))) float;

__device__ __forceinline__ void gl_lds16(const _Float16* g, _Float16* l) {
    __builtin_amdgcn_global_load_lds(
        (const __attribute__((address_space(1))) void*)g,
        (__attribute__((address_space(3))) void*)l, 16, 0, 0);
}

// ---------------------------------------------------------------------------
// fp32 -> fp16 converter, fused: y=0 -> x tensor, y=1..4 -> the 4 weights.
// ---------------------------------------------------------------------------
__global__ __launch_bounds__(256) void cvt5(
    const float* __restrict__ sx,
    const float* __restrict__ s1, const float* __restrict__ s2,
    const float* __restrict__ s3, const float* __restrict__ s4,
    _Float16* __restrict__ dx,
    _Float16* __restrict__ d1, _Float16* __restrict__ d2,
    _Float16* __restrict__ d3, _Float16* __restrict__ d4,
    int n8x, int n8w)
{
    const int y = blockIdx.y;
    const float* s = (y == 0) ? sx : (y == 1) ? s1 : (y == 2) ? s2
                   : (y == 3) ? s3 : s4;
    _Float16*   d = (y == 0) ? dx : (y == 1) ? d1 : (y == 2) ? d2
                   : (y == 3) ? d3 : d4;
    const int n8 = (y == 0) ? n8x : n8w;
    int idx = blockIdx.x * 256 + threadIdx.x;
    if (idx < n8) {
        const float4 a = ((const float4*)s)[idx * 2];
        const float4 b = ((const float4*)s)[idx * 2 + 1];
        half8 h;
        h[0] = (_Float16)a.x; h[1] = (_Float16)a.y;
        h[2] = (_Float16)a.z; h[3] = (_Float16)a.w;
        h[4] = (_Float16)b.x; h[5] = (_Float16)b.y;
        h[6] = (_Float16)b.z; h[7] = (_Float16)b.w;
        ((half8*)d)[idx] = h;
    }
}

// ---------------------------------------------------------------------------
// fp16 MFMA GEMM (m97 structure): C = A @ W^T + bias.
// BN = output-tile width (128 for QKV; 64 for out-proj -> 512 blocks, 2+/CU).
// ---------------------------------------------------------------------------
template <int OUT_HALF, int BN>
__global__ __launch_bounds__(256) void gemm_h(
    const _Float16* __restrict__ A,
    const _Float16* __restrict__ W0, const _Float16* __restrict__ W1,
    const _Float16* __restrict__ W2,
    const float* __restrict__ b0, const float* __restrict__ b1,
    const float* __restrict__ b2,
    void* __restrict__ O0, void* __restrict__ O1, void* __restrict__ O2)
{
    constexpr int K = DM, N = DM, BK = 64;
    constexpr int NF = BN / 32;          // n-frags per wave (4 or 2)

    const _Float16* Wp = (blockIdx.z == 0) ? W0 : (blockIdx.z == 1) ? W1 : W2;
    const float*    bb = (blockIdx.z == 0) ? b0 : (blockIdx.z == 1) ? b1 : b2;
    void*           Op = (blockIdx.z == 0) ? O0 : (blockIdx.z == 1) ? O1 : O2;

    __shared__ _Float16 Asl[128 * BK];   // 16 KB
    __shared__ _Float16 Bsl[BN * BK];    // 16 or 8 KB

    const int tid  = threadIdx.x;
    const int lane = tid & 63;
    const int w    = tid >> 6;          // wave 0..3
    const int wm   = w & 1, wn = w >> 1;
    const int m0   = blockIdx.y * 128;
    const int n0   = blockIdx.x * BN;

    const int l8 = lane >> 3;           // row within 8-row group
    const int lc = lane & 7;            // 16B chunk within row

    floatx4 acc[4][NF];
#pragma unroll
    for (int t = 0; t < 4; ++t)
#pragma unroll
        for (int u = 0; u < NF; ++u) acc[t][u] = (floatx4){0.f, 0.f, 0.f, 0.f};

    for (int k0 = 0; k0 < K; k0 += BK) {
        __syncthreads();                 // prior iter's LDS reads done
#pragma unroll
        for (int i = 0; i < 4; ++i) {    // A rows 0..127
            const int r  = w * 8 + l8 + i * 32;
            const int ca = lc ^ (r & 7);             // swizzled chunk
            gl_lds16(A + (size_t)(m0 + r) * K + k0 + ca * 8,
                     Asl + r * BK + lc * 8);
        }
#pragma unroll
        for (int i = 0; i < BN / 32; ++i) {          // B rows 0..BN-1
            const int r  = w * 8 + l8 + i * 32;
            const int ca = lc ^ (r & 7);
            gl_lds16(Wp + (size_t)(n0 + r) * K + k0 + ca * 8,
                     Bsl + r * BK + lc * 8);
        }
        __syncthreads();                 // drain global_load_lds
#pragma unroll
        for (int kk = 0; kk < BK; kk += 32) {
            half8 af[4], bf[NF];
            const int q = (kk >> 3) + (lane >> 4);   // chunk idx 0..7
#pragma unroll
            for (int t = 0; t < 4; ++t) {
                const int ra = wm * 64 + t * 16 + (lane & 15);
                af[t] = *(const half8*)(Asl + ra * BK + ((q ^ (ra & 7)) << 3));
            }
#pragma unroll
            for (int u = 0; u < NF; ++u) {
                const int rb = wn * (BN / 2) + u * 16 + (lane & 15);
                bf[u] = *(const half8*)(Bsl + rb * BK + ((q ^ (rb & 7)) << 3));
            }
#pragma unroll
            for (int t = 0; t < 4; ++t)
#pragma unroll
                for (int u = 0; u < NF; ++u)
                    acc[t][u] = __builtin_amdgcn_mfma_f32_16x16x32_f16(
                        af[t], bf[u], acc[t][u], 0, 0, 0);
        }
    }

    // epilogue: C/D layout col=lane&15, row=(lane>>4)*4+reg
    const int col0 = n0 + wn * (BN / 2) + (lane & 15);
    const int row0 = m0 + wm * 64 + ((lane >> 4) << 2);
#pragma unroll
    for (int u = 0; u < NF; ++u) {
        const int n = col0 + u * 16;
        const float bias = bb[n];
#pragma unroll
        for (int t = 0; t < 4; ++t) {
            const int m = row0 + t * 16;
#pragma unroll
            for (int r = 0; r < 4; ++r) {
                const float v = acc[t][u][r] + bias;
                if (OUT_HALF)
                    ((_Float16*)Op)[(size_t)(m + r) * N + n] = (_Float16)v;
                else
                    ((float*)Op)[(size_t)(m + r) * N + n] = v;
            }
        }
    }
}

// ---------------------------------------------------------------------------
// Sliding-window attention v11: v10 (nt stores + XCD swizzle, zeros in the
// softmax phase) + R6's verified 53.0 KB LDS layout -> 3 blocks/CU
// (__launch_bounds__(256,3)). With 2 blocks/CU the store pipe idles whenever
// both resident blocks are in stage/QK^T/PV; a third block keeps stores in
// flight. (R6's neutral result for this layout was confounded by L2 thrash
// from cacheable stores — removed by nt in R9.)
//  smem map: [0,34816) K[272][64] -> later Vt[64][288] spans [0,36864)
//            [34816,36864) Q[16][64] (dead before Vt scatter)
//            [36864,54272) S rows, stride 1088 B (272 f32); P fp16 overlay
// ---------------------------------------------------------------------------
__global__ __launch_bounds__(256, 3) void attn_mfma(
    const _Float16* __restrict__ Q, const _Float16* __restrict__ K,
    const _Float16* __restrict__ V, float* __restrict__ attn,
    _Float16* __restrict__ ctx)
{
    const int tid  = threadIdx.x;
    const int lane = tid & 63;
    const int w    = tid >> 6;            // wave 0..3

    // XCD-chunk swizzle (T1); 4096 % 8 == 0 -> bijective
    const int f    = blockIdx.x + 128 * (blockIdx.y + 16 * blockIdx.z);
    const int newf = (f & 7) * 512 + (f >> 3);
    const int qt   = newf & 127;
    const int h    = (newf >> 7) & 15;
    const int b    = newf >> 11;

    const int i0 = qt * 16;
    const int wo = i0 - WN;               // window origin (multiple of 16)

    __shared__ __align__(16) char smem[54272];
    _Float16* KV = (_Float16*)smem;                // K[272][64] / Vt[64][288]
    _Float16* Qs = (_Float16*)(smem + 34816);      // Q[16][64]
    char*     Sb = smem + 36864;                   // S rows, stride 1088 B

    const int l8 = lane >> 3;             // row in 8-row stage group
    const int lc = lane & 7;              // 16B chunk in row

    // ---- phase 1: stage K rows 0..255 (all waves) ----
#pragma unroll
    for (int i = 0; i < 8; ++i) {
        const int r  = w * 8 + l8 + i * 32;
        const int jg = wo + r;
        const int jc = jg < 0 ? 0 : (jg >= SQ ? SQ - 1 : jg);
        const int ca = lc ^ (r & 7);
        gl_lds16(K + ((size_t)(b * SQ + jc)) * DM + h * DH + ca * 8,
                 KV + r * 64 + lc * 8);
    }
    if (w < 2) {                          // K rows 256..271
        const int r  = 256 + w * 8 + l8;
        const int jg = wo + r;
        const int jc = jg >= SQ ? SQ - 1 : jg;
        const int ca = lc ^ (r & 7);
        gl_lds16(K + ((size_t)(b * SQ + jc)) * DM + h * DH + ca * 8,
                 KV + r * 64 + lc * 8);
    } else {                              // Q rows 0..15 (waves 2,3)
        const int r  = (w - 2) * 8 + l8;
        const int ca = lc ^ (r & 7);
        gl_lds16(Q + ((size_t)(b * SQ + i0 + r)) * DM + h * DH + ca * 8,
                 Qs + r * 64 + lc * 8);
    }

    // V window -> registers (288 rows x 8 chunks = 9 tasks/thread exactly)
    half8 vr[9];
#pragma unroll
    for (int it = 0; it < 9; ++it) {
        const int idx = tid + 256 * it;
        const int j = idx >> 3, c8 = idx & 7;
        const int jg = wo + j;
        const int jc = jg < 0 ? 0 : (jg >= SQ ? SQ - 1 : jg);
        vr[it] = *(const half8*)(V + ((size_t)(b * SQ + jc)) * DM + h * DH + c8 * 8);
    }

    __syncthreads();                      // K/Q staged (drains vmcnt)

    // ---- phase 3: QK^T ----
    half8 af0, af1;
    {
        const int row = lane & 15;
        af0 = *(const half8*)(Qs + row * 64 + ((((lane >> 4))     ^ (row & 7)) << 3));
        af1 = *(const half8*)(Qs + row * 64 + (((4 + (lane >> 4)) ^ (row & 7)) << 3));
    }
    for (int t = w; t < 17; t += 4) {
        const int rb = t * 16 + (lane & 15);
        half8 bf0 = *(const half8*)(KV + rb * 64 + ((((lane >> 4))     ^ (rb & 7)) << 3));
        half8 bf1 = *(const half8*)(KV + rb * 64 + (((4 + (lane >> 4)) ^ (rb & 7)) << 3));
        floatx4 acc = (floatx4){0.f, 0.f, 0.f, 0.f};
        acc = __builtin_amdgcn_mfma_f32_16x16x32_f16(af0, bf0, acc, 0, 0, 0);
        acc = __builtin_amdgcn_mfma_f32_16x16x32_f16(af1, bf1, acc, 0, 0, 0);
        const int jloc = t * 16 + (lane & 15);
        const int jg   = wo + jloc;
        const bool inr = (jg >= 0) && (jg < SQ);
#pragma unroll
        for (int r = 0; r < 4; ++r) {
            const int q = ((lane >> 4) << 2) + r;
            const bool valid = ((unsigned)(jloc - q) <= 256u) && inr;
            ((float*)(Sb + q * 1088))[jloc] = valid ? acc[r] * 0.125f : -1e30f;
        }
    }
    __syncthreads();                      // S complete, K reads done

    // ---- phase 5a: scatter V^T into KV (stride 288, low-2-bit swizzle) ----
#pragma unroll
    for (int it = 0; it < 9; ++it) {
        const int idx = tid + 256 * it;
        const int j = idx >> 3, c8 = idx & 7;
        const int jc3 = j >> 3, jl = j & 7;
#pragma unroll
        for (int e = 0; e < 8; ++e) {
            const int d  = c8 * 8 + e;
            const int f2 = (d + (d >> 3)) & 3;
            KV[d * 288 + ((jc3 ^ f2) << 3) + jl] = vr[it][e];
        }
    }

    // ---- phase 5b: softmax + P fp16 overlay + full attn rows (nt) ----
    for (int q = w; q < 16; q += 4) {
        const float* Srow = (const float*)(Sb + q * 1088);
        const float v0 = Srow[lane];
        const float v1 = Srow[lane + 64];
        const float v2 = Srow[lane + 128];
        const float v3 = Srow[lane + 192];
        const float v4 = (lane < 16) ? Srow[lane + 256] : -1e30f;
        float m = fmaxf(fmaxf(fmaxf(v0, v1), fmaxf(v2, v3)), v4);
        m = fmaxf(m, __shfl_xor(m, 32));
        m = fmaxf(m, __shfl_xor(m, 16));
        m = fmaxf(m, __shfl_xor(m, 8));
        m = fmaxf(m, __shfl_xor(m, 4));
        m = fmaxf(m, __shfl_xor(m, 2));
        m = fmaxf(m, __shfl_xor(m, 1));
        float e0 = __expf(v0 - m), e1 = __expf(v1 - m), e2 = __expf(v2 - m),
              e3 = __expf(v3 - m), e4 = __expf(v4 - m);
        float s = ((e0 + e1) + (e2 + e3)) + e4;
        s += __shfl_xor(s, 32); s += __shfl_xor(s, 16); s += __shfl_xor(s, 8);
        s += __shfl_xor(s, 4);  s += __shfl_xor(s, 2);  s += __shfl_xor(s, 1);
        const float inv = 1.0f / s;
        e0 *= inv; e1 *= inv; e2 *= inv; e3 *= inv; e4 *= inv;

        // P fp16 overlay on S row q (640 B used of 1088 B row)
        const int fq = (q + (q >> 3)) & 7;
        _Float16* Prow = (_Float16*)(Sb + q * 1088);
        Prow[((((lane      ) >> 3) ^ fq) << 3) + (lane & 7)] = (_Float16)e0;
        Prow[((((lane +  64) >> 3) ^ fq) << 3) + (lane & 7)] = (_Float16)e1;
        Prow[((((lane + 128) >> 3) ^ fq) << 3) + (lane & 7)] = (_Float16)e2;
        Prow[((((lane + 192) >> 3) ^ fq) << 3) + (lane & 7)] = (_Float16)e3;
        if (lane < 16) {
            Prow[((((lane + 256) >> 3) ^ fq) << 3) + (lane & 7)] = (_Float16)e4;
            // pad MUST order after the S reads it aliases: 0.0f*e4 dep chain
            Prow[((((lane + 272) >> 3) ^ fq) << 3) + (lane & 7)] =
                (_Float16)(0.0f * e4);
        }

        // full attn row: band values + float4 zeros — all non-temporal
        float* arow = attn + ((size_t)(b * NH + h) * SQ + i0 + q) * SQ;
        const int g0 = wo + lane;
        if ((unsigned)(g0      ) < (unsigned)SQ)
            __builtin_nontemporal_store(e0, arow + g0);
        if ((unsigned)(g0 +  64) < (unsigned)SQ)
            __builtin_nontemporal_store(e1, arow + g0 + 64);
        if ((unsigned)(g0 + 128) < (unsigned)SQ)
            __builtin_nontemporal_store(e2, arow + g0 + 128);
        if ((unsigned)(g0 + 192) < (unsigned)SQ)
            __builtin_nontemporal_store(e3, arow + g0 + 192);
        if (lane < 16 && (unsigned)(g0 + 256) < (unsigned)SQ)
            __builtin_nontemporal_store(e4, arow + g0 + 256);
        const int a0 = wo > 0 ? wo : 0;
        const int b0 = (wo + 272 < SQ) ? (wo + 272) : SQ;
        const floatx4 zv = (floatx4){0.f, 0.f, 0.f, 0.f};
        floatx4* za = (floatx4*)arow;
        const int na = a0 >> 2;
        for (int c = lane; c < na; c += 64)
            __builtin_nontemporal_store(zv, za + c);
        floatx4* zb = (floatx4*)(arow + b0);
        const int nb = (SQ - b0) >> 2;
        for (int c = lane; c < nb; c += 64)
            __builtin_nontemporal_store(zv, zb + c);
    }
    __syncthreads();                      // Vt + P complete

    // ---- phase 7: PV (wave w -> d-tile w) ----
    {
        const int rowp = lane & 15;                        // q (A rows)
        const int fp = (rowp + (rowp >> 3)) & 7;
        const int rowv = w * 16 + (lane & 15);             // d (B rows)
        const int fv = (rowv + (rowv >> 3)) & 3;
        floatx4 acc = (floatx4){0.f, 0.f, 0.f, 0.f};
#pragma unroll
        for (int ks = 0; ks < 9; ++ks) {
            const int lch = ks * 4 + (lane >> 4);          // logical chunk 0..35
            half8 ap = *(const half8*)(Sb + rowp * 1088 + ((lch ^ fp) << 4));
            half8 bp = *(const half8*)(KV + rowv * 288 + ((lch ^ fv) << 3));
            acc = __builtin_amdgcn_mfma_f32_16x16x32_f16(ap, bp, acc, 0, 0, 0);
        }
        const int dcol = w * 16 + (lane & 15);
#pragma unroll
        for (int r = 0; r < 4; ++r) {
            const int q = ((lane >> 4) << 2) + r;
            ctx[((size_t)(b * SQ + i0 + q)) * DM + h * DH + dcol] = (_Float16)acc[r];
        }
    }
}

// ---------------------------------------------------------------------------
extern "C" void kernel_launch(void* const* d_in, const int* in_sizes, int n_in,
                              void* d_out, int out_size, void* d_ws, size_t ws_size,
                              hipStream_t stream)
{
    const float* x  = (const float*)d_in[0];
    const float* Wq = (const float*)d_in[1];
    const float* bq = (const float*)d_in[2];
    const float* Wk = (const float*)d_in[3];
    const float* bk = (const float*)d_in[4];
    const float* Wv = (const float*)d_in[5];
    const float* bv = (const float*)d_in[6];
    const float* Wo = (const float*)d_in[7];
    const float* bo = (const float*)d_in[8];

    float* out  = (float*)d_out;
    float* attn = out + (size_t)NB * SQ * DM;

    const size_t tok = (size_t)NB * SQ * DM;   // 4,194,304
    const size_t wsz = (size_t)DM * DM;        // 1,048,576

    _Float16* xh   = (_Float16*)d_ws;
    _Float16* Wqh  = xh   + tok;
    _Float16* Wkh  = Wqh  + wsz;
    _Float16* Wvh  = Wkh  + wsz;
    _Float16* Woh  = Wvh  + wsz;
    _Float16* Qh   = Woh  + wsz;
    _Float16* Kh   = Qh   + tok;
    _Float16* Vh   = Kh   + tok;
    _Float16* ctxh = Vh   + tok;               // total ~50 MB fp16

    // 1) fp32 -> fp16 converts (single fused launch)
    cvt5<<<dim3((int)(tok / 8 / 256), 5), dim3(256), 0, stream>>>(
        x, Wq, Wk, Wv, Wo, xh, Wqh, Wkh, Wvh, Woh,
        (int)(tok / 8), (int)(wsz / 8));

    // 2) QKV projections (fp16 MFMA, fused via grid.z, fp16 out in [B,S,D])
    gemm_h<1, 128><<<dim3(DM / 128, (NB * SQ) / 128, 3), dim3(256), 0, stream>>>(
        xh, Wqh, Wkh, Wvh, bq, bk, bv, Qh, Kh, Vh);

    // 3) banded attention: MFMA QK^T + softmax + full attn rows + MFMA PV
    attn_mfma<<<dim3(SQ / 16, NH, NB), dim3(256), 0, stream>>>(Qh, Kh, Vh, attn, ctxh);

    // 4) output projection (fp16 MFMA, fp32 out; BN=64 -> 512 blocks, 2+/CU)
    gemm_h<0, 64><<<dim3(DM / 64, (NB * SQ) / 128, 1), dim3(256), 0, stream>>>(
        ctxh, Woh, Woh, Woh, bo, bo, bo, out, out, out);
}